// Round 4
// baseline (229.965 us; speedup 1.0000x reference)
//
#include <hip/hip_runtime.h>
#include <math.h>

#define NLEV 8
#define D_DIM 1024

struct TB  { float  t[8]; };   // fp32 z-space thresholds (fast path)
struct TBD { double t[8]; };   // fp64 z-space thresholds (repair path)

// ---- DPP rotate-reduce within 16-lane rows (VALU pipe) ----
template<int CTRL>
__device__ __forceinline__ float ror_add(float v) {
    int r = __builtin_amdgcn_update_dpp(0, __float_as_int(v), CTRL, 0xF, 0xF, true);
    return v + __int_as_float(r);
}
__device__ __forceinline__ float red16(float v) {
    v = ror_add<0x121>(v);   // row_ror:1
    v = ror_add<0x122>(v);   // row_ror:2
    v = ror_add<0x124>(v);   // row_ror:4
    v = ror_add<0x128>(v);   // row_ror:8
    return v;                // all 16 lanes of each row hold the row sum
}
__device__ __forceinline__ float wave_allreduce(float v) {
    v = red16(v);
    v += __shfl_xor(v, 16, 64);
    v += __shfl_xor(v, 32, 64);
    return v;
}

// ---- fp64 inline repair for one row; x already in registers ----
__device__ __forceinline__ void repair_row(
        long row, float4 a0, float4 a1, float4 a2, float4 a3,
        const float* __restrict__ gg, const float* __restrict__ bg,
        const float* __restrict__ Wg, float* __restrict__ outg,
        const TBD& tbd, int lane)
{
    double ds = 0.0, dsq = 0.0;
    #pragma unroll
    for (int j = 0; j < 4; ++j) {
        const float4 a = (j == 0) ? a0 : (j == 1) ? a1 : (j == 2) ? a2 : a3;
        const double x0 = (double)a.x, x1 = (double)a.y;
        const double x2 = (double)a.z, x3 = (double)a.w;
        ds += ((x0 + x1) + (x2 + x3));
        dsq = fma(x0, x0, dsq); dsq = fma(x1, x1, dsq);
        dsq = fma(x2, x2, dsq); dsq = fma(x3, x3, dsq);
    }
    #pragma unroll
    for (int off = 32; off >= 1; off >>= 1) {
        ds  += __shfl_xor(ds, off, 64);
        dsq += __shfl_xor(dsq, off, 64);
    }
    const double mean = ds * (1.0 / 1024.0);
    const double var  = dsq * (1.0 / 1024.0) - mean * mean;
    const double rstd = 1.0 / sqrt(var + 1e-5);

    double dacc[NLEV];
    #pragma unroll
    for (int n = 0; n < NLEV; ++n) dacc[n] = 0.0;
    #pragma unroll
    for (int j = 0; j < 4; ++j) {
        const int col = j * 256 + lane * 4;
        const float4 a = (j == 0) ? a0 : (j == 1) ? a1 : (j == 2) ? a2 : a3;
        const float4 g4 = *(const float4*)(gg + col);
        const float4 b4 = *(const float4*)(bg + col);
        const double y0 = fma(((double)a.x - mean) * rstd, (double)g4.x, (double)b4.x);
        const double y1 = fma(((double)a.y - mean) * rstd, (double)g4.y, (double)b4.y);
        const double y2 = fma(((double)a.z - mean) * rstd, (double)g4.z, (double)b4.z);
        const double y3 = fma(((double)a.w - mean) * rstd, (double)g4.w, (double)b4.w);
        #pragma unroll
        for (int n = 0; n < NLEV; ++n) {
            const float4 w4 = *(const float4*)(Wg + n * D_DIM + col);
            dacc[n] = fma(y0, (double)w4.x, dacc[n]);
            dacc[n] = fma(y1, (double)w4.y, dacc[n]);
            dacc[n] = fma(y2, (double)w4.z, dacc[n]);
            dacc[n] = fma(y3, (double)w4.w, dacc[n]);
        }
    }
    #pragma unroll
    for (int off = 32; off >= 1; off >>= 1) {
        #pragma unroll
        for (int n = 0; n < NLEV; ++n) dacc[n] += __shfl_xor(dacc[n], off, 64);
    }
    if (lane < NLEV) {
        double a0d = (lane & 4) ? dacc[4] : dacc[0];
        double a1d = (lane & 4) ? dacc[5] : dacc[1];
        double a2d = (lane & 4) ? dacc[6] : dacc[2];
        double a3d = (lane & 4) ? dacc[7] : dacc[3];
        double b0d = (lane & 2) ? a2d : a0d;
        double b1d = (lane & 2) ? a3d : a1d;
        const double z = (lane & 1) ? b1d : b0d;
        int c = 0;
        #pragma unroll
        for (int k = 0; k < 8; ++k) c += (z > tbd.t[k]) ? 1 : 0;
        outg[row * NLEV + lane] = (float)(c - 4);
    }
}

// ---- fp32 fast epilogue for one row; returns "ambiguous" flag ----
__device__ __forceinline__ bool fast_epilogue(
        long row, float s, float sq, float Ssel, float C1sel, float C0sel,
        float* __restrict__ outg, const TB& tb, int lane)
{
    bool flag = false;
    if (lane < NLEV) {
        const float mean = s * (1.0f / 1024.0f);
        const float var  = sq * (1.0f / 1024.0f) - mean * mean;
        const float rstd = 1.0f / sqrtf(var + 1e-5f);
        const float z = rstd * (Ssel - mean * C1sel) + C0sel;
        int cnt = 0;
        float mind = 1e30f;
        #pragma unroll
        for (int k = 0; k < 8; ++k) {
            cnt += (z > tb.t[k]) ? 1 : 0;
            mind = fminf(mind, fabsf(z - tb.t[k]));
        }
        outg[row * NLEV + lane] = (float)(cnt - 4);
        flag = (mind < 1.0e-3f);   // fp32 z error ~1e-4 worst case
    }
    return flag;
}

// ---------------- fused: fp32 fast path (row pairs) + inline fp64 repair ----
// R12 = R11 resubmit (R11 failed on container acquisition — infra, not kernel:
// no divergent barrier, wave-uniform repair branch, no graph-capture violation,
// est. ~115-120 VGPR inside the (512,4) 128-VGPR cap).
// Design rationale (from R10 counters: HBM 11%, VALU 25%, LDS-pipe ~26%,
// occ 16% -> latency-bound, nothing saturated):
//  * 64 rows/block -> 512 blocks = exactly 2 blocks/CU ALL resident (prologue
//    paid once, no sequential batches), 8 rows/wave.
//  * pair-processing: one V ds_read feeds TWO rows' FMA chains -> LDS traffic
//    halves, 8 global loads in flight per pair, every dep chain has a twin.
//  * launch_bounds(512,4) pins VGPR<=128 so 16-wave residency can't collapse.
__global__ __launch_bounds__(512, 4) void fsq_fused(
        const float* __restrict__ xg,
        const float* __restrict__ gg,
        const float* __restrict__ bg,
        const float* __restrict__ Wg,
        float* __restrict__ outg,
        int nrows, TB tb, TBD tbd)
{
    __shared__ float Vs[NLEV][D_DIM];     // 32 KB: V = g*W
    __shared__ float redc1[8][NLEV];
    __shared__ float redc0[8][NLEV];

    const int tid  = (int)threadIdx.x;
    const int lane = tid & 63;
    const int wv   = tid >> 6;            // 0..7

    // ---- stage V into LDS; block-reduce C1=sum(g*W), C0=sum(b*W) ----
    {
        const int col = tid * 2;          // 512 threads x 2 cols = 1024
        const float2 g2 = *(const float2*)(gg + col);
        const float2 b2 = *(const float2*)(bg + col);
        float pc1[NLEV], pc0[NLEV];
        #pragma unroll
        for (int n = 0; n < NLEV; ++n) {
            const float2 w2 = *(const float2*)(Wg + n * D_DIM + col);
            float2 v2;
            v2.x = g2.x * w2.x; v2.y = g2.y * w2.y;
            *(float2*)&Vs[n][col] = v2;
            pc1[n] = v2.x + v2.y;
            pc0[n] = b2.x * w2.x + b2.y * w2.y;
        }
        #pragma unroll
        for (int n = 0; n < NLEV; ++n) {
            pc1[n] = wave_allreduce(pc1[n]);
            pc0[n] = wave_allreduce(pc0[n]);
        }
        if (lane == 0) {
            #pragma unroll
            for (int n = 0; n < NLEV; ++n) { redc1[wv][n] = pc1[n]; redc0[wv][n] = pc0[n]; }
        }
    }
    __syncthreads();
    const int nsel = lane & 7;
    float C1sel = 0.f, C0sel = 0.f;
    #pragma unroll
    for (int w = 0; w < 8; ++w) { C1sel += redc1[w][nsel]; C0sel += redc0[w][nsel]; }

    // ---- row loop: 8 rows per wave, processed as 4 pairs ----
    const long wave_row0 = (long)blockIdx.x * 64 + (long)wv * 8;
    const float4* xb = (const float4*)xg;

    for (int p = 0; p < 4; ++p) {
        const long r0 = wave_row0 + 2 * p;
        if (r0 >= nrows) break;
        const long r1 = r0 + 1;
        const bool has1 = (r1 < nrows);

        const float4* xr0 = xb + r0 * (D_DIM / 4);
        const float4* xr1 = xb + (has1 ? r1 : r0) * (D_DIM / 4);
        float4 a0 = xr0[lane];
        float4 a1 = xr0[64 + lane];
        float4 a2 = xr0[128 + lane];
        float4 a3 = xr0[192 + lane];
        float4 b0 = xr1[lane];
        float4 b1 = xr1[64 + lane];
        float4 b2 = xr1[128 + lane];
        float4 b3 = xr1[192 + lane];

        float s0 = 0.f, sq0 = 0.f, s1 = 0.f, sq1 = 0.f;
        float acc0[NLEV], acc1[NLEV];
        #pragma unroll
        for (int n = 0; n < NLEV; ++n) { acc0[n] = 0.f; acc1[n] = 0.f; }

        #pragma unroll
        for (int j = 0; j < 4; ++j) {
            const float4 xa = (j == 0) ? a0 : (j == 1) ? a1 : (j == 2) ? a2 : a3;
            const float4 xc = (j == 0) ? b0 : (j == 1) ? b1 : (j == 2) ? b2 : b3;
            const int vcol = j * 256 + lane * 4;
            s0 += (xa.x + xa.y) + (xa.z + xa.w);
            sq0 = fmaf(xa.x, xa.x, sq0); sq0 = fmaf(xa.y, xa.y, sq0);
            sq0 = fmaf(xa.z, xa.z, sq0); sq0 = fmaf(xa.w, xa.w, sq0);
            s1 += (xc.x + xc.y) + (xc.z + xc.w);
            sq1 = fmaf(xc.x, xc.x, sq1); sq1 = fmaf(xc.y, xc.y, sq1);
            sq1 = fmaf(xc.z, xc.z, sq1); sq1 = fmaf(xc.w, xc.w, sq1);
            #pragma unroll
            for (int n = 0; n < NLEV; ++n) {
                const float4 v4 = *(const float4*)&Vs[n][vcol];  // ds_read_b128, shared by both rows
                acc0[n] = fmaf(xa.x, v4.x, acc0[n]);
                acc0[n] = fmaf(xa.y, v4.y, acc0[n]);
                acc0[n] = fmaf(xa.z, v4.z, acc0[n]);
                acc0[n] = fmaf(xa.w, v4.w, acc0[n]);
                acc1[n] = fmaf(xc.x, v4.x, acc1[n]);
                acc1[n] = fmaf(xc.y, v4.y, acc1[n]);
                acc1[n] = fmaf(xc.z, v4.z, acc1[n]);
                acc1[n] = fmaf(xc.w, v4.w, acc1[n]);
            }
        }

        // within-16 DPP reduce (two independent chains interleave on the VALU)
        s0 = red16(s0); sq0 = red16(sq0);
        s1 = red16(s1); sq1 = red16(sq1);
        #pragma unroll
        for (int n = 0; n < NLEV; ++n) { acc0[n] = red16(acc0[n]); acc1[n] = red16(acc1[n]); }

        float u00 = (lane & 4) ? acc0[4] : acc0[0];
        float u01 = (lane & 4) ? acc0[5] : acc0[1];
        float u02 = (lane & 4) ? acc0[6] : acc0[2];
        float u03 = (lane & 4) ? acc0[7] : acc0[3];
        float w00 = (lane & 2) ? u02 : u00;
        float w01 = (lane & 2) ? u03 : u01;
        float Ssel0 = (lane & 1) ? w01 : w00;

        float u10 = (lane & 4) ? acc1[4] : acc1[0];
        float u11 = (lane & 4) ? acc1[5] : acc1[1];
        float u12 = (lane & 4) ? acc1[6] : acc1[2];
        float u13 = (lane & 4) ? acc1[7] : acc1[3];
        float w10 = (lane & 2) ? u12 : u10;
        float w11 = (lane & 2) ? u13 : u11;
        float Ssel1 = (lane & 1) ? w11 : w10;

        Ssel0 += __shfl_xor(Ssel0, 16, 64); Ssel0 += __shfl_xor(Ssel0, 32, 64);
        Ssel1 += __shfl_xor(Ssel1, 16, 64); Ssel1 += __shfl_xor(Ssel1, 32, 64);
        s0    += __shfl_xor(s0, 16, 64);    s0    += __shfl_xor(s0, 32, 64);
        sq0   += __shfl_xor(sq0, 16, 64);   sq0   += __shfl_xor(sq0, 32, 64);
        s1    += __shfl_xor(s1, 16, 64);    s1    += __shfl_xor(s1, 32, 64);
        sq1   += __shfl_xor(sq1, 16, 64);   sq1   += __shfl_xor(sq1, 32, 64);

        const bool flag0 = fast_epilogue(r0, s0, sq0, Ssel0, C1sel, C0sel, outg, tb, lane);
        const bool flag1 = has1 ? fast_epilogue(r1, s1, sq1, Ssel1, C1sel, C0sel, outg, tb, lane)
                                : false;

        const unsigned long long bal0 = __ballot(flag0);
        const unsigned long long bal1 = __ballot(flag1);
        if (bal0 != 0ULL)          repair_row(r0, a0, a1, a2, a3, gg, bg, Wg, outg, tbd, lane);
        if (bal1 != 0ULL && has1)  repair_row(r1, b0, b1, b2, b3, gg, bg, Wg, outg, tbd, lane);
    }
}

extern "C" void kernel_launch(void* const* d_in, const int* in_sizes, int n_in,
                              void* d_out, int out_size, void* d_ws, size_t ws_size,
                              hipStream_t stream) {
    (void)n_in; (void)out_size; (void)d_ws; (void)ws_size;  // workspace UNUSED
    const float* regrs = (const float*)d_in[0];
    const float* ln_w  = (const float*)d_in[1];
    const float* ln_b  = (const float*)d_in[2];
    const float* W     = (const float*)d_in[3];
    float* out = (float*)d_out;

    const int nrows = in_sizes[0] / D_DIM;  // 32768
    const int nblocks = (nrows + 63) / 64;  // 64 rows/block -> 512 blocks (2/CU, all resident)

    TB tb; TBD tbd;
    for (int k = 0; k < 8; ++k) {
        const double y = ((double)k - 3.5) / 3.996;
        tbd.t[k] = atanh(y);           // fp64 z-space rounding boundaries
        tb.t[k]  = (float)tbd.t[k];
    }

    fsq_fused<<<nblocks, 512, 0, stream>>>(regrs, ln_w, ln_b, W, out, nrows, tb, tbd);
}

// Round 5
// 213.408 us; speedup vs baseline: 1.0776x; 1.0776x over previous
//
#include <hip/hip_runtime.h>
#include <math.h>

#define NLEV 8
#define D_DIM 1024

struct TB  { float  t[8]; };   // fp32 z-space thresholds (fast path)
struct TBD { double t[8]; };   // fp64 z-space thresholds (repair path)

// ---- DPP rotate-reduce within 16-lane rows (VALU pipe) ----
template<int CTRL>
__device__ __forceinline__ float ror_add(float v) {
    int r = __builtin_amdgcn_update_dpp(0, __float_as_int(v), CTRL, 0xF, 0xF, true);
    return v + __int_as_float(r);
}
__device__ __forceinline__ float red16(float v) {
    v = ror_add<0x121>(v);   // row_ror:1
    v = ror_add<0x122>(v);   // row_ror:2
    v = ror_add<0x124>(v);   // row_ror:4
    v = ror_add<0x128>(v);   // row_ror:8
    return v;                // all 16 lanes of each row hold the row sum
}
__device__ __forceinline__ float wave_allreduce(float v) {
    v = red16(v);
    v += __shfl_xor(v, 16, 64);
    v += __shfl_xor(v, 32, 64);
    return v;
}

// ---- fp64 inline repair for one row; x already in registers ----
__device__ __forceinline__ void repair_row(
        long row, float4 a0, float4 a1, float4 a2, float4 a3,
        const float* __restrict__ gg, const float* __restrict__ bg,
        const float* __restrict__ Wg, float* __restrict__ outg,
        const TBD& tbd, int lane)
{
    double ds = 0.0, dsq = 0.0;
    #pragma unroll
    for (int j = 0; j < 4; ++j) {
        const float4 a = (j == 0) ? a0 : (j == 1) ? a1 : (j == 2) ? a2 : a3;
        const double x0 = (double)a.x, x1 = (double)a.y;
        const double x2 = (double)a.z, x3 = (double)a.w;
        ds += ((x0 + x1) + (x2 + x3));
        dsq = fma(x0, x0, dsq); dsq = fma(x1, x1, dsq);
        dsq = fma(x2, x2, dsq); dsq = fma(x3, x3, dsq);
    }
    #pragma unroll
    for (int off = 32; off >= 1; off >>= 1) {
        ds  += __shfl_xor(ds, off, 64);
        dsq += __shfl_xor(dsq, off, 64);
    }
    const double mean = ds * (1.0 / 1024.0);
    const double var  = dsq * (1.0 / 1024.0) - mean * mean;
    const double rstd = 1.0 / sqrt(var + 1e-5);

    double dacc[NLEV];
    #pragma unroll
    for (int n = 0; n < NLEV; ++n) dacc[n] = 0.0;
    #pragma unroll
    for (int j = 0; j < 4; ++j) {
        const int col = j * 256 + lane * 4;
        const float4 a = (j == 0) ? a0 : (j == 1) ? a1 : (j == 2) ? a2 : a3;
        const float4 g4 = *(const float4*)(gg + col);
        const float4 b4 = *(const float4*)(bg + col);
        const double y0 = fma(((double)a.x - mean) * rstd, (double)g4.x, (double)b4.x);
        const double y1 = fma(((double)a.y - mean) * rstd, (double)g4.y, (double)b4.y);
        const double y2 = fma(((double)a.z - mean) * rstd, (double)g4.z, (double)b4.z);
        const double y3 = fma(((double)a.w - mean) * rstd, (double)g4.w, (double)b4.w);
        #pragma unroll
        for (int n = 0; n < NLEV; ++n) {
            const float4 w4 = *(const float4*)(Wg + n * D_DIM + col);
            dacc[n] = fma(y0, (double)w4.x, dacc[n]);
            dacc[n] = fma(y1, (double)w4.y, dacc[n]);
            dacc[n] = fma(y2, (double)w4.z, dacc[n]);
            dacc[n] = fma(y3, (double)w4.w, dacc[n]);
        }
    }
    #pragma unroll
    for (int off = 32; off >= 1; off >>= 1) {
        #pragma unroll
        for (int n = 0; n < NLEV; ++n) dacc[n] += __shfl_xor(dacc[n], off, 64);
    }
    if (lane < NLEV) {
        double a0d = (lane & 4) ? dacc[4] : dacc[0];
        double a1d = (lane & 4) ? dacc[5] : dacc[1];
        double a2d = (lane & 4) ? dacc[6] : dacc[2];
        double a3d = (lane & 4) ? dacc[7] : dacc[3];
        double b0d = (lane & 2) ? a2d : a0d;
        double b1d = (lane & 2) ? a3d : a1d;
        const double z = (lane & 1) ? b1d : b0d;
        int c = 0;
        #pragma unroll
        for (int k = 0; k < 8; ++k) c += (z > tbd.t[k]) ? 1 : 0;
        outg[row * NLEV + lane] = (float)(c - 4);
    }
}

// ---- fp32 fast epilogue for one row; returns "ambiguous" flag ----
__device__ __forceinline__ bool fast_epilogue(
        long row, float s, float sq, float Ssel, float C1sel, float C0sel,
        float* __restrict__ outg, const TB& tb, int lane)
{
    bool flag = false;
    if (lane < NLEV) {
        const float mean = s * (1.0f / 1024.0f);
        const float var  = sq * (1.0f / 1024.0f) - mean * mean;
        const float rstd = 1.0f / sqrtf(var + 1e-5f);
        const float z = rstd * (Ssel - mean * C1sel) + C0sel;
        int cnt = 0;
        float mind = 1e30f;
        #pragma unroll
        for (int k = 0; k < 8; ++k) {
            cnt += (z > tb.t[k]) ? 1 : 0;
            mind = fminf(mind, fabsf(z - tb.t[k]));
        }
        outg[row * NLEV + lane] = (float)(cnt - 4);
        flag = (mind < 1.0e-3f);   // fp32 z error ~1e-4 worst case
    }
    return flag;
}

// ---------------- fused: fp32 fast path (row pairs) + inline fp64 repair ----
// R13 post-mortem of R12: __launch_bounds__(512,4) behaves with CUDA semantics
// (min BLOCKS/CU): 4 blocks x 8 waves = 8 waves/SIMD -> 64-VGPR cap -> the
// paired kernel's ~120-130 live regs SPILLED (VGPR_Count=64, WRITE_SIZE
// 1.0->25.9 MB = scratch traffic) -> 78->90 us regression.
// Single-variable fix: (512,2) -> min 2 blocks/CU = 4 waves/SIMD = 128-VGPR
// cap. 2 blocks/CU is exactly the all-resident config (512 blocks/256 CU).
// Design (from R10 counters: HBM 11%, VALU 25%, LDS-pipe ~26%, latency-bound):
//  * 64 rows/block, 8 rows/wave, prologue paid once, no sequential batches.
//  * pair-processing: one V ds_read feeds TWO rows' FMA chains -> LDS traffic
//    halves, 8 global loads in flight per pair, every dep chain has a twin.
__global__ __launch_bounds__(512, 2) void fsq_fused(
        const float* __restrict__ xg,
        const float* __restrict__ gg,
        const float* __restrict__ bg,
        const float* __restrict__ Wg,
        float* __restrict__ outg,
        int nrows, TB tb, TBD tbd)
{
    __shared__ float Vs[NLEV][D_DIM];     // 32 KB: V = g*W
    __shared__ float redc1[8][NLEV];
    __shared__ float redc0[8][NLEV];

    const int tid  = (int)threadIdx.x;
    const int lane = tid & 63;
    const int wv   = tid >> 6;            // 0..7

    // ---- stage V into LDS; block-reduce C1=sum(g*W), C0=sum(b*W) ----
    {
        const int col = tid * 2;          // 512 threads x 2 cols = 1024
        const float2 g2 = *(const float2*)(gg + col);
        const float2 b2 = *(const float2*)(bg + col);
        float pc1[NLEV], pc0[NLEV];
        #pragma unroll
        for (int n = 0; n < NLEV; ++n) {
            const float2 w2 = *(const float2*)(Wg + n * D_DIM + col);
            float2 v2;
            v2.x = g2.x * w2.x; v2.y = g2.y * w2.y;
            *(float2*)&Vs[n][col] = v2;
            pc1[n] = v2.x + v2.y;
            pc0[n] = b2.x * w2.x + b2.y * w2.y;
        }
        #pragma unroll
        for (int n = 0; n < NLEV; ++n) {
            pc1[n] = wave_allreduce(pc1[n]);
            pc0[n] = wave_allreduce(pc0[n]);
        }
        if (lane == 0) {
            #pragma unroll
            for (int n = 0; n < NLEV; ++n) { redc1[wv][n] = pc1[n]; redc0[wv][n] = pc0[n]; }
        }
    }
    __syncthreads();
    const int nsel = lane & 7;
    float C1sel = 0.f, C0sel = 0.f;
    #pragma unroll
    for (int w = 0; w < 8; ++w) { C1sel += redc1[w][nsel]; C0sel += redc0[w][nsel]; }

    // ---- row loop: 8 rows per wave, processed as 4 pairs ----
    const long wave_row0 = (long)blockIdx.x * 64 + (long)wv * 8;
    const float4* xb = (const float4*)xg;

    for (int p = 0; p < 4; ++p) {
        const long r0 = wave_row0 + 2 * p;
        if (r0 >= nrows) break;
        const long r1 = r0 + 1;
        const bool has1 = (r1 < nrows);

        const float4* xr0 = xb + r0 * (D_DIM / 4);
        const float4* xr1 = xb + (has1 ? r1 : r0) * (D_DIM / 4);
        float4 a0 = xr0[lane];
        float4 a1 = xr0[64 + lane];
        float4 a2 = xr0[128 + lane];
        float4 a3 = xr0[192 + lane];
        float4 b0 = xr1[lane];
        float4 b1 = xr1[64 + lane];
        float4 b2 = xr1[128 + lane];
        float4 b3 = xr1[192 + lane];

        float s0 = 0.f, sq0 = 0.f, s1 = 0.f, sq1 = 0.f;
        float acc0[NLEV], acc1[NLEV];
        #pragma unroll
        for (int n = 0; n < NLEV; ++n) { acc0[n] = 0.f; acc1[n] = 0.f; }

        #pragma unroll
        for (int j = 0; j < 4; ++j) {
            const float4 xa = (j == 0) ? a0 : (j == 1) ? a1 : (j == 2) ? a2 : a3;
            const float4 xc = (j == 0) ? b0 : (j == 1) ? b1 : (j == 2) ? b2 : b3;
            const int vcol = j * 256 + lane * 4;
            s0 += (xa.x + xa.y) + (xa.z + xa.w);
            sq0 = fmaf(xa.x, xa.x, sq0); sq0 = fmaf(xa.y, xa.y, sq0);
            sq0 = fmaf(xa.z, xa.z, sq0); sq0 = fmaf(xa.w, xa.w, sq0);
            s1 += (xc.x + xc.y) + (xc.z + xc.w);
            sq1 = fmaf(xc.x, xc.x, sq1); sq1 = fmaf(xc.y, xc.y, sq1);
            sq1 = fmaf(xc.z, xc.z, sq1); sq1 = fmaf(xc.w, xc.w, sq1);
            #pragma unroll
            for (int n = 0; n < NLEV; ++n) {
                const float4 v4 = *(const float4*)&Vs[n][vcol];  // ds_read_b128, shared by both rows
                acc0[n] = fmaf(xa.x, v4.x, acc0[n]);
                acc0[n] = fmaf(xa.y, v4.y, acc0[n]);
                acc0[n] = fmaf(xa.z, v4.z, acc0[n]);
                acc0[n] = fmaf(xa.w, v4.w, acc0[n]);
                acc1[n] = fmaf(xc.x, v4.x, acc1[n]);
                acc1[n] = fmaf(xc.y, v4.y, acc1[n]);
                acc1[n] = fmaf(xc.z, v4.z, acc1[n]);
                acc1[n] = fmaf(xc.w, v4.w, acc1[n]);
            }
        }

        // within-16 DPP reduce (two independent chains interleave on the VALU)
        s0 = red16(s0); sq0 = red16(sq0);
        s1 = red16(s1); sq1 = red16(sq1);
        #pragma unroll
        for (int n = 0; n < NLEV; ++n) { acc0[n] = red16(acc0[n]); acc1[n] = red16(acc1[n]); }

        float u00 = (lane & 4) ? acc0[4] : acc0[0];
        float u01 = (lane & 4) ? acc0[5] : acc0[1];
        float u02 = (lane & 4) ? acc0[6] : acc0[2];
        float u03 = (lane & 4) ? acc0[7] : acc0[3];
        float w00 = (lane & 2) ? u02 : u00;
        float w01 = (lane & 2) ? u03 : u01;
        float Ssel0 = (lane & 1) ? w01 : w00;

        float u10 = (lane & 4) ? acc1[4] : acc1[0];
        float u11 = (lane & 4) ? acc1[5] : acc1[1];
        float u12 = (lane & 4) ? acc1[6] : acc1[2];
        float u13 = (lane & 4) ? acc1[7] : acc1[3];
        float w10 = (lane & 2) ? u12 : u10;
        float w11 = (lane & 2) ? u13 : u11;
        float Ssel1 = (lane & 1) ? w11 : w10;

        Ssel0 += __shfl_xor(Ssel0, 16, 64); Ssel0 += __shfl_xor(Ssel0, 32, 64);
        Ssel1 += __shfl_xor(Ssel1, 16, 64); Ssel1 += __shfl_xor(Ssel1, 32, 64);
        s0    += __shfl_xor(s0, 16, 64);    s0    += __shfl_xor(s0, 32, 64);
        sq0   += __shfl_xor(sq0, 16, 64);   sq0   += __shfl_xor(sq0, 32, 64);
        s1    += __shfl_xor(s1, 16, 64);    s1    += __shfl_xor(s1, 32, 64);
        sq1   += __shfl_xor(sq1, 16, 64);   sq1   += __shfl_xor(sq1, 32, 64);

        const bool flag0 = fast_epilogue(r0, s0, sq0, Ssel0, C1sel, C0sel, outg, tb, lane);
        const bool flag1 = has1 ? fast_epilogue(r1, s1, sq1, Ssel1, C1sel, C0sel, outg, tb, lane)
                                : false;

        const unsigned long long bal0 = __ballot(flag0);
        const unsigned long long bal1 = __ballot(flag1);
        if (bal0 != 0ULL)          repair_row(r0, a0, a1, a2, a3, gg, bg, Wg, outg, tbd, lane);
        if (bal1 != 0ULL && has1)  repair_row(r1, b0, b1, b2, b3, gg, bg, Wg, outg, tbd, lane);
    }
}

extern "C" void kernel_launch(void* const* d_in, const int* in_sizes, int n_in,
                              void* d_out, int out_size, void* d_ws, size_t ws_size,
                              hipStream_t stream) {
    (void)n_in; (void)out_size; (void)d_ws; (void)ws_size;  // workspace UNUSED
    const float* regrs = (const float*)d_in[0];
    const float* ln_w  = (const float*)d_in[1];
    const float* ln_b  = (const float*)d_in[2];
    const float* W     = (const float*)d_in[3];
    float* out = (float*)d_out;

    const int nrows = in_sizes[0] / D_DIM;  // 32768
    const int nblocks = (nrows + 63) / 64;  // 64 rows/block -> 512 blocks (2/CU, all resident)

    TB tb; TBD tbd;
    for (int k = 0; k < 8; ++k) {
        const double y = ((double)k - 3.5) / 3.996;
        tbd.t[k] = atanh(y);           // fp64 z-space rounding boundaries
        tb.t[k]  = (float)tbd.t[k];
    }

    fsq_fused<<<nblocks, 512, 0, stream>>>(regrs, ln_w, ln_b, W, out, nrows, tb, tbd);
}